// Round 1
// 563.965 us; speedup vs baseline: 1.0057x; 1.0057x over previous
//
#include <hip/hip_runtime.h>

// SX controlled gate on 16 qudits, dim=3, ctrl axis 2 (stride 3^13),
// obj axis 5 (stride 3^10). Gate matrix is real; action per flat index n:
//   d2 = digit(n, axis2), d5 = digit(n, axis5)
//   d2 != 1          -> out[n] = in[n]
//   d2 == 1, d5 == 0 -> out[n] = in[n + 3^10]
//   d2 == 1, d5 == 1 -> out[n] = in[n - 3^10]
//   d2 == 1, d5 == 2 -> out[n] = 0            (u overwrites the diagonal)
// Applied independently to qs_real -> out_re and qs_imag -> out_im.
//
// This version: 16 elements per thread (64B per array), and 4B-aligned
// vector loads (dwordx4) on the shifted path instead of scalar dwords.

#define P10 59049u           // 3^10, the contiguous chunk size
#define P16 43046721u        // 3^16, elements per array

// 4-byte-aligned float4: gfx9+ global loads only need 4B alignment, so the
// compiler can emit global_load_dwordx4 for the odd-element-offset reads.
struct __attribute__((aligned(4))) f4u { float x, y, z, w; };

__global__ __launch_bounds__(256) void sx_apply_kernel(
    const float* __restrict__ re_in, const float* __restrict__ im_in,
    float* __restrict__ re_out, float* __restrict__ im_out)
{
    unsigned tid = blockIdx.x * blockDim.x + threadIdx.x;
    unsigned n = tid * 16u;              // group base (16 consecutive elements)
    if (n >= P16) return;

    unsigned q  = n / P10;               // chunk id
    unsigned r  = n - q * P10;           // offset within chunk
    unsigned d5 = q % 3u;
    unsigned d2 = (q / 27u) % 3u;        // 3^13 = 3^10 * 27

    if (r <= P10 - 16u) {
        // all 16 elements share the same chunk -> uniform digits
        if (d2 != 1u) {
            const float4* ar = (const float4*)(re_in + n);
            const float4* ai = (const float4*)(im_in + n);
            float4 r0 = ar[0], r1 = ar[1], r2 = ar[2], r3 = ar[3];
            float4 i0 = ai[0], i1 = ai[1], i2 = ai[2], i3 = ai[3];
            float4* br = (float4*)(re_out + n);
            float4* bi = (float4*)(im_out + n);
            br[0] = r0; br[1] = r1; br[2] = r2; br[3] = r3;
            bi[0] = i0; bi[1] = i1; bi[2] = i2; bi[3] = i3;
        } else if (d5 == 2u) {
            float4 z = make_float4(0.f, 0.f, 0.f, 0.f);
            float4* br = (float4*)(re_out + n);
            float4* bi = (float4*)(im_out + n);
            br[0] = z; br[1] = z; br[2] = z; br[3] = z;
            bi[0] = z; bi[1] = z; bi[2] = z; bi[3] = z;
        } else {
            // source group is the same r inside the neighboring chunk:
            // contiguous, in-bounds, but only 4B-aligned (P10 is odd)
            unsigned s = (d5 == 0u) ? (n + P10) : (n - P10);
            const f4u* ar = (const f4u*)(re_in + s);
            const f4u* ai = (const f4u*)(im_in + s);
            f4u r0 = ar[0], r1 = ar[1], r2 = ar[2], r3 = ar[3];
            f4u i0 = ai[0], i1 = ai[1], i2 = ai[2], i3 = ai[3];
            float4* br = (float4*)(re_out + n);
            float4* bi = (float4*)(im_out + n);
            br[0] = make_float4(r0.x, r0.y, r0.z, r0.w);
            br[1] = make_float4(r1.x, r1.y, r1.z, r1.w);
            br[2] = make_float4(r2.x, r2.y, r2.z, r2.w);
            br[3] = make_float4(r3.x, r3.y, r3.z, r3.w);
            bi[0] = make_float4(i0.x, i0.y, i0.z, i0.w);
            bi[1] = make_float4(i1.x, i1.y, i1.z, i1.w);
            bi[2] = make_float4(i2.x, i2.y, i2.z, i2.w);
            bi[3] = make_float4(i3.x, i3.y, i3.z, i3.w);
        }
    } else {
        // group straddles a chunk boundary (or is the final partial group):
        // ~1 group per chunk boundary, 729 total -> negligible, keep scalar
        #pragma unroll 4
        for (unsigned j = 0; j < 16u; ++j) {
            unsigned m = n + j;
            if (m >= P16) break;
            unsigned qq  = m / P10;
            unsigned dd5 = qq % 3u;
            unsigned dd2 = (qq / 27u) % 3u;
            float a, b;
            if (dd2 != 1u) {
                a = re_in[m]; b = im_in[m];
            } else if (dd5 == 2u) {
                a = 0.f; b = 0.f;
            } else {
                unsigned s = (dd5 == 0u) ? (m + P10) : (m - P10);
                a = re_in[s]; b = im_in[s];
            }
            re_out[m] = a;
            im_out[m] = b;
        }
    }
}

extern "C" void kernel_launch(void* const* d_in, const int* in_sizes, int n_in,
                              void* d_out, int out_size, void* d_ws, size_t ws_size,
                              hipStream_t stream)
{
    const float* re_in = (const float*)d_in[0];
    const float* im_in = (const float*)d_in[1];
    float* re_out = (float*)d_out;
    float* im_out = (float*)d_out + P16;

    unsigned groups = (P16 + 15u) / 16u;          // 2,690,421
    unsigned blocks = (groups + 255u) / 256u;     // 10,510
    sx_apply_kernel<<<blocks, 256, 0, stream>>>(re_in, im_in, re_out, im_out);
}